// Round 6
// baseline (708.730 us; speedup 1.0000x reference)
//
#include <hip/hip_runtime.h>

// Loihi SNN, 3 layers of (GEMM -> Loihi scan -> delay).
// Round 6: 8-phase-style deep-pipelined MFMA GEMM (T2+T3+T4+T5 per catalog),
// with W-planes STACKED along M (single A stream): W2 = [W_hi; W_mid], M2=2C.
// Scans sum plane pairs (X[c] + X[c+C]) and K-split partials in fixed order.
//
// GEMM schedule: BK=32 K-tiles, 3-deep LDS ring (96KB), 2 phases per K-tile:
//   {ds_read frags || issue 2 global_load_lds -> barrier -> 16 MFMA -> barrier}
// boundary s_waitcnt vmcnt(4) (counted, never 0 mid-loop).
// LDS granule-XOR swizzle (gc ^= row&3) applied as: inverse-swizzled GLOBAL
// source + swizzled ds_read (linear gload_lds dest)  [rule 21].

typedef unsigned short u16;
typedef unsigned int u32;
typedef __attribute__((ext_vector_type(8))) short short8;
typedef __attribute__((ext_vector_type(4))) float f32x4;

#define GLOAD16(g, l)                                                         \
    __builtin_amdgcn_global_load_lds(                                         \
        (const __attribute__((address_space(1))) u32*)(g),                    \
        (__attribute__((address_space(3))) u32*)(l), 16, 0, 0)

__device__ __forceinline__ u16 f2bf_trunc(float x) {
    return (u16)(__float_as_uint(x) >> 16);
}

// ---------------- W -> stacked 2-plane RNE split ----------------
// W2[c][k] = RNE_bf16(w); W2[C+c][k] = RNE_bf16(w - hi)
__global__ void split_w2s(const float* __restrict__ W, u16* __restrict__ W2,
                          int C, int K, int KLD)
{
    const int c = blockIdx.y;
    const int k = blockIdx.x * 256 + threadIdx.x;
    if (k >= KLD) return;
    float w = (k < K) ? W[(size_t)c * K + k] : 0.f;
    u32 b  = __float_as_uint(w);
    u32 hb = (b + 0x7FFFu + ((b >> 16) & 1u)) & 0xFFFF0000u;
    float r = w - __uint_as_float(hb);
    u32 rb = __float_as_uint(r);
    u32 mb = (rb + 0x7FFFu + ((rb >> 16) & 1u)) & 0xFFFF0000u;
    W2[(size_t)c * KLD + k]            = (u16)(hb >> 16);
    W2[((size_t)C + c) * KLD + k]      = (u16)(mb >> 16);
}

// ------- spikes fp32 [n][I][400] -> bf16 [n*400+t][KLD] (transpose) -------
__global__ __launch_bounds__(256) void cvt_sp(const float* __restrict__ S,
                                              u16* __restrict__ Sp,
                                              int I, int KLD)
{
    __shared__ u16 tile[64][80];
    const int n  = blockIdx.z;
    const int i0 = blockIdx.y * 64;
    const int t0 = blockIdx.x * 64;
    const int tid = threadIdx.x;

    const int il = tid >> 2;       // input row (i) within tile
    const int q  = tid & 3;
    const int gi = i0 + il;
    const bool iok = gi < I;
    const float* srow = S + ((size_t)n * I + gi) * 400 + t0;

    #pragma unroll
    for (int s = 0; s < 4; ++s) {
        const int fi = s * 4 + q;      // float4 index 0..15 (64B contig per quad)
        const int tl = fi * 4;
        float4 v = make_float4(0.f, 0.f, 0.f, 0.f);
        if (iok && (t0 + tl) < 400)
            v = *(const float4*)(srow + tl);
        tile[tl + 0][il] = f2bf_trunc(v.x);
        tile[tl + 1][il] = f2bf_trunc(v.y);
        tile[tl + 2][il] = f2bf_trunc(v.z);
        tile[tl + 3][il] = f2bf_trunc(v.w);
    }
    __syncthreads();

    const int tl = tid >> 2;       // output row (t)
    const int iq = tid & 3;        // 16-wide i chunk
    const int t  = t0 + tl;
    const int go = i0 + iq * 16;
    if (t < 400 && go < KLD) {
        u16* dst = Sp + (size_t)(n * 400 + t) * KLD + go;
        *(short8*)(dst)     = *(const short8*)&tile[tl][iq * 16];
        *(short8*)(dst + 8) = *(const short8*)&tile[tl][iq * 16 + 8];
    }
}

// ---------------- deep-pipelined bf16 MFMA GEMM ----------------
// X[z][nt][c] = sum_{k in chunk z} A[c][k] * B[nt][k]
// 256(M) x 256(N) tile, BK=32, 8 waves (2M x 4N), wave = 128x64 output.
__global__ __launch_bounds__(512, 2) void gemm8(
    const u16* __restrict__ A,   // [M2][KLD]
    const u16* __restrict__ B,   // [12800][KLD]
    float* __restrict__ Xbase,   // [z][12800][M2]
    int M2, int KLD, int ktPerZ, int ktTotal)
{
    __shared__ u16 lds[49152];   // A ring: 3x8192 u16 @0 ; B ring: 3x8192 @24576

    // ---- bijective XCD-aware block swizzle (nwg % 8 == 0 in all launches) ----
    const int Dx = gridDim.x, Dy = gridDim.y;
    int f = blockIdx.x + Dx * (blockIdx.y + Dy * blockIdx.z);
    const int nwg = Dx * Dy * gridDim.z;
    f = (f & 7) * (nwg >> 3) + (f >> 3);
    const int bx = f % Dx;
    const int by = (f / Dx) % Dy;
    const int bz = f / (Dx * Dy);

    const int c0  = bx * 256;
    const int nt0 = by * 256;
    const int kt0 = bz * ktPerZ;
    const int nk  = min(ktTotal - kt0, ktPerZ);
    float* __restrict__ X = Xbase + (size_t)bz * 12800 * M2;

    const int tid  = threadIdx.x;
    const int lane = tid & 63, w = tid >> 6;

    // staging: granule g = j*512 + tid; row = g>>2; src granule-col inverse-swz
    const int sr  = tid >> 2;                  // 0..127 (j adds 128)
    const int sgc = (tid & 3) ^ (sr & 3);
    const u16* gA0 = A + (size_t)(c0 + sr) * KLD + (size_t)kt0 * 32 + sgc * 8;
    const u16* gA1 = gA0 + (size_t)128 * KLD;
    const u16* gB0 = B + (size_t)(nt0 + sr) * KLD + (size_t)kt0 * 32 + sgc * 8;
    const u16* gB1 = gB0 + (size_t)128 * KLD;
    u16* const lA0 = &lds[0     + w * 512];
    u16* const lA1 = &lds[4096  + w * 512];
    u16* const lB0 = &lds[24576 + w * 512];
    u16* const lB1 = &lds[24576 + 4096 + w * 512];

#define STAGE_A(i, b) { GLOAD16(gA0 + (size_t)(i) * 32, lA0 + (b) * 8192);    \
                        GLOAD16(gA1 + (size_t)(i) * 32, lA1 + (b) * 8192); }
#define STAGE_B(i, b) { GLOAD16(gB0 + (size_t)(i) * 32, lB0 + (b) * 8192);    \
                        GLOAD16(gB1 + (size_t)(i) * 32, lB1 + (b) * 8192); }
#define FENCE() asm volatile("" ::: "memory")

    // fragment read offsets (swizzled granule col: ks ^ (row&3))
    const int wm = w >> 2, wn = w & 3;
    const int l15 = lane & 15, l16 = lane >> 4;
    const int swz  = (l16 ^ (l15 & 3)) * 8;
    const int aOff = (wm * 128 + l15) * 32 + swz;        // + mf*512 + b*8192
    const int bOff = 24576 + (wn * 64 + l15) * 32 + swz; // + nf*512 + b*8192

    f32x4 acc[8][4];
    #pragma unroll
    for (int i = 0; i < 8; ++i)
        #pragma unroll
        for (int j = 0; j < 4; ++j)
            acc[i][j] = (f32x4){0.f, 0.f, 0.f, 0.f};

    // prologue: stage tiles 0 and 1
    STAGE_A(0, 0); STAGE_B(0, 0);
    if (nk > 1) { STAGE_A(1, 1); STAGE_B(1, 1); }

    for (int i = 0; i < nk; ++i) {
        const int b  = i % 3;
        const int bb = b * 8192;
        const int bs = (i + 2) % 3;

        // ---- K-tile boundary: counted vmcnt, collective via barrier ----
        if (i < nk - 1) { asm volatile("s_waitcnt vmcnt(4)" ::: "memory"); }
        else            { asm volatile("s_waitcnt vmcnt(0)" ::: "memory"); }
        __builtin_amdgcn_s_barrier();
        FENCE();

        // ---- phase 1: A m-frags 0..3 + B n-frags 0..3 ; stage A(i+2) ----
        short8 a1[4], bf[4];
        #pragma unroll
        for (int mf = 0; mf < 4; ++mf)
            a1[mf] = *(const short8*)&lds[bb + aOff + mf * 512];
        #pragma unroll
        for (int nf = 0; nf < 4; ++nf)
            bf[nf] = *(const short8*)&lds[bb + bOff + nf * 512];
        if (i + 2 < nk) STAGE_A(i + 2, bs);
        FENCE();
        __builtin_amdgcn_s_barrier();
        FENCE();
        __builtin_amdgcn_s_setprio(1);
        #pragma unroll
        for (int mf = 0; mf < 4; ++mf)
            #pragma unroll
            for (int nf = 0; nf < 4; ++nf)
                acc[mf][nf] = __builtin_amdgcn_mfma_f32_16x16x32_bf16(
                    a1[mf], bf[nf], acc[mf][nf], 0, 0, 0);
        __builtin_amdgcn_s_setprio(0);
        __builtin_amdgcn_s_barrier();
        FENCE();

        // ---- phase 2: A m-frags 4..7 (B reused in regs) ; stage B(i+2) ----
        short8 a2[4];
        #pragma unroll
        for (int mf = 0; mf < 4; ++mf)
            a2[mf] = *(const short8*)&lds[bb + aOff + (mf + 4) * 512];
        if (i + 2 < nk) STAGE_B(i + 2, bs);
        FENCE();
        __builtin_amdgcn_s_barrier();
        FENCE();
        __builtin_amdgcn_s_setprio(1);
        #pragma unroll
        for (int mf = 0; mf < 4; ++mf)
            #pragma unroll
            for (int nf = 0; nf < 4; ++nf)
                acc[mf + 4][nf] = __builtin_amdgcn_mfma_f32_16x16x32_bf16(
                    a2[mf], bf[nf], acc[mf + 4][nf], 0, 0, 0);
        __builtin_amdgcn_s_setprio(0);
        __builtin_amdgcn_s_barrier();
        FENCE();
    }

    // epilogue: D col=lane&15 -> nt, row=(lane>>4)*4+reg -> c (m89-verified)
    #pragma unroll
    for (int mf = 0; mf < 8; ++mf) {
        const int c = c0 + wm * 128 + mf * 16 + l16 * 4;
        #pragma unroll
        for (int nf = 0; nf < 4; ++nf) {
            const int nt = nt0 + wn * 64 + nf * 16 + l15;
            *(f32x4*)&X[(size_t)nt * M2 + c] = acc[mf][nf];
        }
    }
#undef STAGE_A
#undef STAGE_B
#undef FENCE
}

// ---------------- Loihi scans (8-deep pipelined loads, 64-thr blocks) ------
__device__ __forceinline__ float loihi_step(float xt, float& u, float& v)
{
    u = truncf(u * 0.75f) + 64.f * xt;
    v = truncf(v * 0.96875f) + u;
    if (v >= 5120.f) { v = 0.f; return 1.f; }
    return 0.f;
}

// scan_ab: tact (1 partial, stacked pair) + vis (2 partials, stacked pairs)
//          -> combi spikes Sc [nt][1024] bf16
__global__ __launch_bounds__(64) void scan_ab(const float* __restrict__ Xt,
                                              const float* __restrict__ Xv,
                                              u16* __restrict__ Sc)
{
    const int gid = blockIdx.x * 64 + threadIdx.x;   // 32*1024 threads
    const int n = gid >> 10;
    const int c = gid & 1023;
    const size_t PS = (size_t)12800 * 1024;          // vis partial stride

    u16* srow = Sc + (size_t)(n * 400) * 1024 + c;
    srow[0] = 0;

    float buf[8];
    float u = 0.f, v = 0.f;

    if (c < 512) {
        const float* xr = Xt + (size_t)(n * 400) * 1024 + c;
        #pragma unroll
        for (int d = 0; d < 8; ++d) {
            const size_t o = (size_t)d * 1024;
            buf[d] = xr[o] + xr[o + 512];
        }
        #pragma unroll 8
        for (int t = 0; t < 400; ++t) {
            const float xt = buf[t & 7];
            const int tn = t + 8;
            float nx = 0.f;
            if (tn < 400) {
                const size_t o = (size_t)tn * 1024;
                nx = xr[o] + xr[o + 512];
            }
            buf[t & 7] = nx;
            const float sp = loihi_step(xt, u, v);
            if (t < 399) srow[(size_t)(t + 1) * 1024] = (sp != 0.f) ? (u16)0x3F80 : (u16)0;
        }
    } else {
        const float* xr = Xv + (size_t)(n * 400) * 1024 + (c - 512);
        #pragma unroll
        for (int d = 0; d < 8; ++d) {
            const size_t o = (size_t)d * 1024;
            buf[d] = (xr[o] + xr[o + 512]) + (xr[o + PS] + xr[o + PS + 512]);
        }
        #pragma unroll 8
        for (int t = 0; t < 400; ++t) {
            const float xt = buf[t & 7];
            const int tn = t + 8;
            float nx = 0.f;
            if (tn < 400) {
                const size_t o = (size_t)tn * 1024;
                nx = (xr[o] + xr[o + 512]) + (xr[o + PS] + xr[o + PS + 512]);
            }
            buf[t & 7] = nx;
            const float sp = loihi_step(xt, u, v);
            if (t < 399) srow[(size_t)(t + 1) * 1024] = (sp != 0.f) ? (u16)0x3F80 : (u16)0;
        }
    }
}

// scan_c: combi (2 partials, stacked pairs at +256) -> out [n][c][t]
__global__ __launch_bounds__(64) void scan_c(const float* __restrict__ Xc,
                                             float* __restrict__ out)
{
    const int gid = blockIdx.x * 64 + threadIdx.x;   // 32*256 threads
    const int n = gid >> 8;
    const int c = gid & 255;
    const size_t PS = (size_t)12800 * 512;
    const float* xr = Xc + (size_t)(n * 400) * 512 + c;
    float* orow = out + ((size_t)n * 256 + c) * 400;
    orow[0] = 0.f;

    float buf[8];
    #pragma unroll
    for (int d = 0; d < 8; ++d) {
        const size_t o = (size_t)d * 512;
        buf[d] = (xr[o] + xr[o + 256]) + (xr[o + PS] + xr[o + PS + 256]);
    }
    float u = 0.f, v = 0.f;
    #pragma unroll 8
    for (int t = 0; t < 400; ++t) {
        const float xt = buf[t & 7];
        const int tn = t + 8;
        float nx = 0.f;
        if (tn < 400) {
            const size_t o = (size_t)tn * 512;
            nx = (xr[o] + xr[o + 256]) + (xr[o + PS] + xr[o + PS + 256]);
        }
        buf[t & 7] = nx;
        const float sp = loihi_step(xt, u, v);
        if (t < 399) orow[t + 1] = sp;
    }
}

extern "C" void kernel_launch(void* const* d_in, const int* in_sizes, int n_in,
                              void* d_out, int out_size, void* d_ws, size_t ws_size,
                              hipStream_t stream)
{
    const float* tact   = (const float*)d_in[0];  // [32][156][400]
    const float* vis    = (const float*)d_in[1];  // [32][6300][400]
    const float* W_tact = (const float*)d_in[2];  // [512][156]
    const float* W_vis  = (const float*)d_in[3];  // [512][6300]
    const float* W_comb = (const float*)d_in[4];  // [256][1024]
    float* out = (float*)d_out;                   // [32][256][400]

    const int NT = 32 * 400;            // 12800
    const int Ktp = 160;                // tact K pad (5 K-tiles)
    const int Kvp = 6304;               // vis K pad (197 K-tiles)
    const int Kc  = 1024;               // combi K (32 K-tiles)

    // ---- workspace carve-up: 284,622,848 B (identical to round 5) ----
    char* p = (char*)d_ws;
    u16* Sv  = (u16*)p;                p += (size_t)NT * Kvp * 2;        // 161.4MB
    u16* St  = (u16*)p;                p += (size_t)NT * Ktp * 2;        //   4.1MB
    u16* Wt2 = (u16*)p;                p += (size_t)1024 * Ktp * 2;      //   0.33MB
    u16* Wv2 = (u16*)p;                p += (size_t)1024 * Kvp * 2;      //  12.9MB
    u16* Wc2 = (u16*)p;                p += (size_t)512 * Kc * 2;        //   1.05MB
    float* Xv = (float*)p;             p += (size_t)2 * NT * 1024 * 4;   // 104.9MB
    // aliases into Sv region (Sv dead after vis gemm; tact gemm runs after):
    float* Xt = (float*)Sv;                                        // [NT][1024] f32 52.4MB
    u16*   Sc = (u16*)((char*)Sv + (size_t)NT * 1024 * 4);         // [NT][1024] bf16 26.2MB
    float* Xc = (float*)((char*)Sv + (size_t)NT * 1024 * 4 + (size_t)NT * 1024 * 2); // [2][NT][512] f32 52.4MB

    // 1) weight splits (stacked 2 RNE planes)
    split_w2s<<<dim3((Kvp + 255) / 256, 512), 256, 0, stream>>>(W_vis,  Wv2, 512, 6300, Kvp);
    split_w2s<<<dim3((Ktp + 255) / 256, 512), 256, 0, stream>>>(W_tact, Wt2, 512, 156,  Ktp);
    split_w2s<<<dim3((Kc  + 255) / 256, 256), 256, 0, stream>>>(W_comb, Wc2, 256, 1024, Kc);

    // 2) spike transpose+convert
    cvt_sp<<<dim3(7, (Kvp + 63) / 64, 32), 256, 0, stream>>>(vis,  Sv, 6300, Kvp);
    cvt_sp<<<dim3(7, (Ktp + 63) / 64, 32), 256, 0, stream>>>(tact, St, 156,  Ktp);

    // 3) vis GEMM first (reads Sv), THEN tact GEMM (writes Xt over dead Sv)
    gemm8<<<dim3(1024 / 256, NT / 256, 2), 512, 0, stream>>>(Wv2, Sv, Xv, 1024, Kvp, 99, 197);
    gemm8<<<dim3(1024 / 256, NT / 256, 1), 512, 0, stream>>>(Wt2, St, Xt, 1024, Ktp, 5, 5);

    // 4) scan layers 1+2 -> combi spikes (bf16, [nt][1024])
    scan_ab<<<dim3((32 * 1024) / 64), 64, 0, stream>>>(Xt, Xv, Sc);

    // 5) combi GEMM (z=2 K-chunks of 16 tiles) + scan -> out
    gemm8<<<dim3(512 / 256, NT / 256, 2), 512, 0, stream>>>(Wc2, Sc, Xc, 512, Kc, 16, 32);
    scan_c<<<dim3((32 * 256) / 64), 64, 0, stream>>>(Xc, out);

    (void)in_sizes; (void)n_in; (void)out_size; (void)ws_size;
}

// Round 7
// 688.293 us; speedup vs baseline: 1.0297x; 1.0297x over previous
//
#include <hip/hip_runtime.h>

// Loihi SNN, 3 layers of (GEMM -> Loihi scan -> delay).
// Round 7: fix the LDS swizzle (key (row>>1)&3, giving 2-way=free bank slots
// for ds_read_b128 at BK=32) and drop the two redundant post-MFMA barriers
// (boundary vmcnt+barrier covers all 3-ring overwrite windows).
//
// W-planes stacked along M (single A stream): W2 = [W_hi; W_mid], M2=2C.
// Scans sum plane pairs (X[c] + X[c+C]) and K-split partials in fixed order.

typedef unsigned short u16;
typedef unsigned int u32;
typedef __attribute__((ext_vector_type(8))) short short8;
typedef __attribute__((ext_vector_type(4))) float f32x4;

#define GLOAD16(g, l)                                                         \
    __builtin_amdgcn_global_load_lds(                                         \
        (const __attribute__((address_space(1))) u32*)(g),                    \
        (__attribute__((address_space(3))) u32*)(l), 16, 0, 0)

__device__ __forceinline__ u16 f2bf_trunc(float x) {
    return (u16)(__float_as_uint(x) >> 16);
}

// ---------------- W -> stacked 2-plane RNE split ----------------
__global__ void split_w2s(const float* __restrict__ W, u16* __restrict__ W2,
                          int C, int K, int KLD)
{
    const int c = blockIdx.y;
    const int k = blockIdx.x * 256 + threadIdx.x;
    if (k >= KLD) return;
    float w = (k < K) ? W[(size_t)c * K + k] : 0.f;
    u32 b  = __float_as_uint(w);
    u32 hb = (b + 0x7FFFu + ((b >> 16) & 1u)) & 0xFFFF0000u;
    float r = w - __uint_as_float(hb);
    u32 rb = __float_as_uint(r);
    u32 mb = (rb + 0x7FFFu + ((rb >> 16) & 1u)) & 0xFFFF0000u;
    W2[(size_t)c * KLD + k]       = (u16)(hb >> 16);
    W2[((size_t)C + c) * KLD + k] = (u16)(mb >> 16);
}

// ------- spikes fp32 [n][I][400] -> bf16 [n*400+t][KLD] (transpose) -------
__global__ __launch_bounds__(256) void cvt_sp(const float* __restrict__ S,
                                              u16* __restrict__ Sp,
                                              int I, int KLD)
{
    __shared__ u16 tile[64][80];
    const int n  = blockIdx.z;
    const int i0 = blockIdx.y * 64;
    const int t0 = blockIdx.x * 64;
    const int tid = threadIdx.x;

    const int il = tid >> 2;
    const int q  = tid & 3;
    const int gi = i0 + il;
    const bool iok = gi < I;
    const float* srow = S + ((size_t)n * I + gi) * 400 + t0;

    #pragma unroll
    for (int s = 0; s < 4; ++s) {
        const int fi = s * 4 + q;
        const int tl = fi * 4;
        float4 v = make_float4(0.f, 0.f, 0.f, 0.f);
        if (iok && (t0 + tl) < 400)
            v = *(const float4*)(srow + tl);
        tile[tl + 0][il] = f2bf_trunc(v.x);
        tile[tl + 1][il] = f2bf_trunc(v.y);
        tile[tl + 2][il] = f2bf_trunc(v.z);
        tile[tl + 3][il] = f2bf_trunc(v.w);
    }
    __syncthreads();

    const int tl = tid >> 2;
    const int iq = tid & 3;
    const int t  = t0 + tl;
    const int go = i0 + iq * 16;
    if (t < 400 && go < KLD) {
        u16* dst = Sp + (size_t)(n * 400 + t) * KLD + go;
        *(short8*)(dst)     = *(const short8*)&tile[tl][iq * 16];
        *(short8*)(dst + 8) = *(const short8*)&tile[tl][iq * 16 + 8];
    }
}

// ---------------- deep-pipelined bf16 MFMA GEMM ----------------
// X[z][nt][c] = sum_{k in chunk z} A[c][k] * B[nt][k]
// 256(M) x 256(N) tile, BK=32, 8 waves (2M x 4N), wave = 128x64 output.
__global__ __launch_bounds__(512, 2) void gemm8(
    const u16* __restrict__ A,   // [M2][KLD]
    const u16* __restrict__ B,   // [12800][KLD]
    float* __restrict__ Xbase,   // [z][12800][M2]
    int M2, int KLD, int ktPerZ, int ktTotal)
{
    __shared__ u16 lds[49152];   // A ring: 3x8192 u16 @0 ; B ring: 3x8192 @24576

    // bijective XCD-aware block swizzle (all launches have nwg % 8 == 0)
    const int Dx = gridDim.x, Dy = gridDim.y;
    int f = blockIdx.x + Dx * (blockIdx.y + Dy * blockIdx.z);
    const int nwg = Dx * Dy * gridDim.z;
    f = (f & 7) * (nwg >> 3) + (f >> 3);
    const int bx = f % Dx;
    const int by = (f / Dx) % Dy;
    const int bz = f / (Dx * Dy);

    const int c0  = bx * 256;
    const int nt0 = by * 256;
    const int kt0 = bz * ktPerZ;
    const int nk  = min(ktTotal - kt0, ktPerZ);
    float* __restrict__ X = Xbase + (size_t)bz * 12800 * M2;

    const int tid  = threadIdx.x;
    const int lane = tid & 63, w = tid >> 6;

    // staging: LDS granule (row=tid>>2, gc=tid&3) <- global granule-col
    // inverse-swizzled with key (row>>1)&3  [both-sides-or-neither, rule 21]
    const int sr  = tid >> 2;                       // 0..127 (half j adds 128)
    const int sgc = (tid & 3) ^ ((sr >> 1) & 3);
    const u16* gA0 = A + (size_t)(c0 + sr) * KLD + (size_t)kt0 * 32 + sgc * 8;
    const u16* gA1 = gA0 + (size_t)128 * KLD;
    const u16* gB0 = B + (size_t)(nt0 + sr) * KLD + (size_t)kt0 * 32 + sgc * 8;
    const u16* gB1 = gB0 + (size_t)128 * KLD;
    u16* const lA0 = &lds[0     + w * 512];
    u16* const lA1 = &lds[4096  + w * 512];
    u16* const lB0 = &lds[24576 + w * 512];
    u16* const lB1 = &lds[24576 + 4096 + w * 512];

#define STAGE_A(i, b) { GLOAD16(gA0 + (size_t)(i) * 32, lA0 + (b) * 8192);    \
                        GLOAD16(gA1 + (size_t)(i) * 32, lA1 + (b) * 8192); }
#define STAGE_B(i, b) { GLOAD16(gB0 + (size_t)(i) * 32, lB0 + (b) * 8192);    \
                        GLOAD16(gB1 + (size_t)(i) * 32, lB1 + (b) * 8192); }
#define FENCE() asm volatile("" ::: "memory")

    // fragment reads: granule col = l16 ^ ((row>>1)&3); row ≡ l15 (mod 16)
    const int wm = w >> 2, wn = w & 3;
    const int l15 = lane & 15, l16 = lane >> 4;
    const int swz  = (l16 ^ ((l15 >> 1) & 3)) * 8;
    const int aOff = (wm * 128 + l15) * 32 + swz;        // + mf*512 + b*8192
    const int bOff = 24576 + (wn * 64 + l15) * 32 + swz; // + nf*512 + b*8192

    f32x4 acc[8][4];
    #pragma unroll
    for (int i = 0; i < 8; ++i)
        #pragma unroll
        for (int j = 0; j < 4; ++j)
            acc[i][j] = (f32x4){0.f, 0.f, 0.f, 0.f};

    // prologue: stage tiles 0 and 1
    STAGE_A(0, 0); STAGE_B(0, 0);
    if (nk > 1) { STAGE_A(1, 1); STAGE_B(1, 1); }

    for (int i = 0; i < nk; ++i) {
        const int bb = (i % 3) * 8192;
        const int bs = (i + 2) % 3;

        // K-tile boundary: counted vmcnt (never 0 mid-loop), one barrier
        if (i < nk - 1) { asm volatile("s_waitcnt vmcnt(4)" ::: "memory"); }
        else            { asm volatile("s_waitcnt vmcnt(0)" ::: "memory"); }
        __builtin_amdgcn_s_barrier();
        FENCE();

        // phase 1: ds_read A m-frags 0..3 + B n-frags 0..3 ; stage A(i+2)
        short8 a1[4], bf[4];
        #pragma unroll
        for (int mf = 0; mf < 4; ++mf)
            a1[mf] = *(const short8*)&lds[bb + aOff + mf * 512];
        #pragma unroll
        for (int nf = 0; nf < 4; ++nf)
            bf[nf] = *(const short8*)&lds[bb + bOff + nf * 512];
        if (i + 2 < nk) STAGE_A(i + 2, bs);
        FENCE();
        __builtin_amdgcn_s_barrier();   // phase alignment pre-MFMA
        FENCE();
        __builtin_amdgcn_s_setprio(1);
        #pragma unroll
        for (int mf = 0; mf < 4; ++mf)
            #pragma unroll
            for (int nf = 0; nf < 4; ++nf)
                acc[mf][nf] = __builtin_amdgcn_mfma_f32_16x16x32_bf16(
                    a1[mf], bf[nf], acc[mf][nf], 0, 0, 0);
        __builtin_amdgcn_s_setprio(0);
        FENCE();

        // phase 2: ds_read A m-frags 4..7 (B reused in regs) ; stage B(i+2)
        short8 a2[4];
        #pragma unroll
        for (int mf = 0; mf < 4; ++mf)
            a2[mf] = *(const short8*)&lds[bb + aOff + (mf + 4) * 512];
        if (i + 2 < nk) STAGE_B(i + 2, bs);
        FENCE();
        __builtin_amdgcn_s_barrier();   // phase alignment pre-MFMA
        FENCE();
        __builtin_amdgcn_s_setprio(1);
        #pragma unroll
        for (int mf = 0; mf < 4; ++mf)
            #pragma unroll
            for (int nf = 0; nf < 4; ++nf)
                acc[mf + 4][nf] = __builtin_amdgcn_mfma_f32_16x16x32_bf16(
                    a2[mf], bf[nf], acc[mf + 4][nf], 0, 0, 0);
        __builtin_amdgcn_s_setprio(0);
        FENCE();
    }

    // epilogue: D col=lane&15 -> nt, row=(lane>>4)*4+reg -> c (m89-verified)
    #pragma unroll
    for (int mf = 0; mf < 8; ++mf) {
        const int c = c0 + wm * 128 + mf * 16 + l16 * 4;
        #pragma unroll
        for (int nf = 0; nf < 4; ++nf) {
            const int nt = nt0 + wn * 64 + nf * 16 + l15;
            *(f32x4*)&X[(size_t)nt * M2 + c] = acc[mf][nf];
        }
    }
#undef STAGE_A
#undef STAGE_B
#undef FENCE
}

// ---------------- Loihi scans (8-deep pipelined loads, 64-thr blocks) ------
__device__ __forceinline__ float loihi_step(float xt, float& u, float& v)
{
    u = truncf(u * 0.75f) + 64.f * xt;
    v = truncf(v * 0.96875f) + u;
    if (v >= 5120.f) { v = 0.f; return 1.f; }
    return 0.f;
}

// scan_ab: tact (stacked pair) + vis (2 partials, stacked pairs) -> Sc bf16
__global__ __launch_bounds__(64) void scan_ab(const float* __restrict__ Xt,
                                              const float* __restrict__ Xv,
                                              u16* __restrict__ Sc)
{
    const int gid = blockIdx.x * 64 + threadIdx.x;   // 32*1024 threads
    const int n = gid >> 10;
    const int c = gid & 1023;
    const size_t PS = (size_t)12800 * 1024;          // vis partial stride

    u16* srow = Sc + (size_t)(n * 400) * 1024 + c;
    srow[0] = 0;

    float buf[8];
    float u = 0.f, v = 0.f;

    if (c < 512) {
        const float* xr = Xt + (size_t)(n * 400) * 1024 + c;
        #pragma unroll
        for (int d = 0; d < 8; ++d) {
            const size_t o = (size_t)d * 1024;
            buf[d] = xr[o] + xr[o + 512];
        }
        #pragma unroll 8
        for (int t = 0; t < 400; ++t) {
            const float xt = buf[t & 7];
            const int tn = t + 8;
            float nx = 0.f;
            if (tn < 400) {
                const size_t o = (size_t)tn * 1024;
                nx = xr[o] + xr[o + 512];
            }
            buf[t & 7] = nx;
            const float sp = loihi_step(xt, u, v);
            if (t < 399) srow[(size_t)(t + 1) * 1024] = (sp != 0.f) ? (u16)0x3F80 : (u16)0;
        }
    } else {
        const float* xr = Xv + (size_t)(n * 400) * 1024 + (c - 512);
        #pragma unroll
        for (int d = 0; d < 8; ++d) {
            const size_t o = (size_t)d * 1024;
            buf[d] = (xr[o] + xr[o + 512]) + (xr[o + PS] + xr[o + PS + 512]);
        }
        #pragma unroll 8
        for (int t = 0; t < 400; ++t) {
            const float xt = buf[t & 7];
            const int tn = t + 8;
            float nx = 0.f;
            if (tn < 400) {
                const size_t o = (size_t)tn * 1024;
                nx = (xr[o] + xr[o + 512]) + (xr[o + PS] + xr[o + PS + 512]);
            }
            buf[t & 7] = nx;
            const float sp = loihi_step(xt, u, v);
            if (t < 399) srow[(size_t)(t + 1) * 1024] = (sp != 0.f) ? (u16)0x3F80 : (u16)0;
        }
    }
}

// scan_c: combi (2 partials, stacked pairs at +256) -> out [n][c][t]
__global__ __launch_bounds__(64) void scan_c(const float* __restrict__ Xc,
                                             float* __restrict__ out)
{
    const int gid = blockIdx.x * 64 + threadIdx.x;   // 32*256 threads
    const int n = gid >> 8;
    const int c = gid & 255;
    const size_t PS = (size_t)12800 * 512;
    const float* xr = Xc + (size_t)(n * 400) * 512 + c;
    float* orow = out + ((size_t)n * 256 + c) * 400;
    orow[0] = 0.f;

    float buf[8];
    #pragma unroll
    for (int d = 0; d < 8; ++d) {
        const size_t o = (size_t)d * 512;
        buf[d] = (xr[o] + xr[o + 256]) + (xr[o + PS] + xr[o + PS + 256]);
    }
    float u = 0.f, v = 0.f;
    #pragma unroll 8
    for (int t = 0; t < 400; ++t) {
        const float xt = buf[t & 7];
        const int tn = t + 8;
        float nx = 0.f;
        if (tn < 400) {
            const size_t o = (size_t)tn * 512;
            nx = (xr[o] + xr[o + 256]) + (xr[o + PS] + xr[o + PS + 256]);
        }
        buf[t & 7] = nx;
        const float sp = loihi_step(xt, u, v);
        if (t < 399) orow[t + 1] = sp;
    }
}

extern "C" void kernel_launch(void* const* d_in, const int* in_sizes, int n_in,
                              void* d_out, int out_size, void* d_ws, size_t ws_size,
                              hipStream_t stream)
{
    const float* tact   = (const float*)d_in[0];  // [32][156][400]
    const float* vis    = (const float*)d_in[1];  // [32][6300][400]
    const float* W_tact = (const float*)d_in[2];  // [512][156]
    const float* W_vis  = (const float*)d_in[3];  // [512][6300]
    const float* W_comb = (const float*)d_in[4];  // [256][1024]
    float* out = (float*)d_out;                   // [32][256][400]

    const int NT = 32 * 400;            // 12800
    const int Ktp = 160;                // tact K pad (5 K-tiles)
    const int Kvp = 6304;               // vis K pad (197 K-tiles)
    const int Kc  = 1024;               // combi K (32 K-tiles)

    // ---- workspace carve-up: identical to rounds 5/6 ----
    char* p = (char*)d_ws;
    u16* Sv  = (u16*)p;                p += (size_t)NT * Kvp * 2;        // 161.4MB
    u16* St  = (u16*)p;                p += (size_t)NT * Ktp * 2;        //   4.1MB
    u16* Wt2 = (u16*)p;                p += (size_t)1024 * Ktp * 2;
    u16* Wv2 = (u16*)p;                p += (size_t)1024 * Kvp * 2;      //  12.9MB
    u16* Wc2 = (u16*)p;                p += (size_t)512 * Kc * 2;
    float* Xv = (float*)p;             p += (size_t)2 * NT * 1024 * 4;   // 104.9MB
    // aliases into Sv region (Sv dead after vis gemm; tact gemm runs after):
    float* Xt = (float*)Sv;                                        // [NT][1024] f32
    u16*   Sc = (u16*)((char*)Sv + (size_t)NT * 1024 * 4);         // [NT][1024] bf16
    float* Xc = (float*)((char*)Sv + (size_t)NT * 1024 * 4 + (size_t)NT * 1024 * 2); // [2][NT][512]

    // 1) weight splits (stacked 2 RNE planes)
    split_w2s<<<dim3((Kvp + 255) / 256, 512), 256, 0, stream>>>(W_vis,  Wv2, 512, 6300, Kvp);
    split_w2s<<<dim3((Ktp + 255) / 256, 512), 256, 0, stream>>>(W_tact, Wt2, 512, 156,  Ktp);
    split_w2s<<<dim3((Kc  + 255) / 256, 256), 256, 0, stream>>>(W_comb, Wc2, 256, 1024, Kc);

    // 2) spike transpose+convert
    cvt_sp<<<dim3(7, (Kvp + 63) / 64, 32), 256, 0, stream>>>(vis,  Sv, 6300, Kvp);
    cvt_sp<<<dim3(7, (Ktp + 63) / 64, 32), 256, 0, stream>>>(tact, St, 156,  Ktp);

    // 3) vis GEMM first (reads Sv), THEN tact GEMM (writes Xt over dead Sv)
    gemm8<<<dim3(1024 / 256, NT / 256, 2), 512, 0, stream>>>(Wv2, Sv, Xv, 1024, Kvp, 99, 197);
    gemm8<<<dim3(1024 / 256, NT / 256, 1), 512, 0, stream>>>(Wt2, St, Xt, 1024, Ktp, 5, 5);

    // 4) scan layers 1+2 -> combi spikes (bf16, [nt][1024])
    scan_ab<<<dim3((32 * 1024) / 64), 64, 0, stream>>>(Xt, Xv, Sc);

    // 5) combi GEMM (z=2 K-chunks of 16 tiles) + scan -> out
    gemm8<<<dim3(512 / 256, NT / 256, 2), 512, 0, stream>>>(Wc2, Sc, Xc, 512, Kc, 16, 32);
    scan_c<<<dim3((32 * 256) / 64), 64, 0, stream>>>(Xc, out);

    (void)in_sizes; (void)n_in; (void)out_size; (void)ws_size;
}